// Round 1
// baseline (169.122 us; speedup 1.0000x reference)
//
#include <hip/hip_runtime.h>

// Problem constants (setup_inputs is fixed)
#define BATCH 2
#define NTXT  2048
#define TMED  4
#define MMED  256
#define TM    (TMED * MMED)      // 1024 kv rows per batch
#define DIM   1024
#define NH    16
#define DHD   64
#define KVW   2048               // k|v concatenated width
#define RMAX  256                // max real rows per batch handled by fast path
#define RT    32                 // row-tile parallelism for heavy-path kernels

typedef _Float16 f16x8 __attribute__((ext_vector_type(8)));
typedef float    f32x4 __attribute__((ext_vector_type(4)));

#define GLOAD_LDS16(g, l)                                                  \
  __builtin_amdgcn_global_load_lds(                                        \
      (const __attribute__((address_space(1))) unsigned int*)(g),          \
      (__attribute__((address_space(3))) unsigned int*)(l), 16, 0, 0)

// ---------------------------------------------------------------------------
// K1: blocks 0..1   : inclusive scan of locations -> txt_time + segment
//     blocks 2..257 : img16 = (f16)image + per-block column partial sums
//                     ipart[b*128+rt][c] (256 blocks -> full-chip BW, no atomics)
//     blocks 258..769: Wkv (K x N f32) -> WkvT (N x K f16) transpose
// ---------------------------------------------------------------------------
__global__ __launch_bounds__(1024) void k1_scan_cvt_tr(
    const int* __restrict__ loc, const float* __restrict__ image,
    const float* __restrict__ Wkv, int* __restrict__ tt, int* __restrict__ seg,
    float* __restrict__ ipart, _Float16* __restrict__ img16,
    _Float16* __restrict__ WkvT) {
  __shared__ int buf[NTXT];
  __shared__ int s_start, s_end;
  __shared__ float tile[64][65];
  const int idx = blockIdx.x;
  const int tid = threadIdx.x;
  if (idx < BATCH) {
    // ---- scan ----
    const int b = idx;
    if (tid == 0) { s_start = NTXT; s_end = NTXT; }
    buf[tid]        = loc[b * NTXT + tid];
    buf[tid + 1024] = loc[b * NTXT + tid + 1024];
    __syncthreads();
    for (int off = 1; off < NTXT; off <<= 1) {
      int a0 = (tid >= off) ? buf[tid - off] : 0;
      int a1 = buf[tid + 1024 - off];
      __syncthreads();
      buf[tid] += a0;
      buf[tid + 1024] += a1;
      __syncthreads();
    }
    const int v0 = buf[tid], v1 = buf[tid + 1024];
    tt[b * NTXT + tid]        = v0;
    tt[b * NTXT + tid + 1024] = v1;
    if (v0 >= 1) atomicMin(&s_start, tid);
    if (v0 >= 5) atomicMin(&s_end, tid);
    if (v1 >= 1) atomicMin(&s_start, tid + 1024);
    if (v1 >= 5) atomicMin(&s_end, tid + 1024);
    __syncthreads();
    if (tid == 0) {
      seg[b * 2]     = s_start;
      seg[b * 2 + 1] = s_end - s_start;
    }
  } else if (idx < BATCH + 256) {
    // ---- image convert + partial column sums ----
    const int j = idx - BATCH;           // 0..255
    const int b = j >> 7, rt = j & 127;  // 128 row-tiles of 8 per batch
    const size_t base = (size_t)(b * TM + rt * 8) * DIM + tid;
    const float* p = image + base;
    _Float16* q = img16 + base;
    float s = 0.f;
#pragma unroll
    for (int r = 0; r < 8; r++) {
      const float v = p[(size_t)r * DIM];
      s += v;
      q[(size_t)r * DIM] = (_Float16)v;
    }
    ipart[(size_t)(b * 128 + rt) * DIM + tid] = s;
  } else {
    // ---- transpose+convert Wkv (64x64 tiles, 1024 threads) ----
    const int j2 = idx - BATCH - 256;    // 0..511
    const int k0 = (j2 & 15) * 64, n0 = (j2 >> 4) * 64;
    const int r = tid >> 4, c4 = (tid & 15) * 4;
    const float4 v = *reinterpret_cast<const float4*>(
        Wkv + (size_t)(k0 + r) * KVW + n0 + c4);
    tile[r][c4 + 0] = v.x; tile[r][c4 + 1] = v.y;
    tile[r][c4 + 2] = v.z; tile[r][c4 + 3] = v.w;
    __syncthreads();
    if (tid < 512) {
      const int n = tid >> 3, kc = (tid & 7) * 8;
      f16x8 h;
#pragma unroll
      for (int u = 0; u < 8; u++) h[u] = (_Float16)tile[kc + u][n];
      *reinterpret_cast<f16x8*>(WkvT + (size_t)(n0 + n) * DIM + k0 + kc) = h;
    }
  }
}

// ---------------------------------------------------------------------------
// K2: blocks 0..63  : LayerNorm of real rows -> tn
//     blocks 64..127: vbar[b,e] += (reduce ipart -> ibar chunk) @ Wkv_v
// ---------------------------------------------------------------------------
__global__ __launch_bounds__(256) void k2_prep(
    const float* __restrict__ Wkv, const float* __restrict__ text,
    const float* __restrict__ gamma, const float* __restrict__ beta,
    const int* __restrict__ seg, const float* __restrict__ ipart,
    float* __restrict__ tn, float* __restrict__ vbar) {
  __shared__ float red[256];
  const int idx = blockIdx.x;
  const int tid = threadIdx.x;
  if (idx < 64) {
    // ---- LayerNorm of real rows ----
    const int b = idx >> 5, rt = idx & 31;
    const int i0 = seg[b * 2];
    const int cnt = min(seg[b * 2 + 1], RMAX);
    for (int r = rt; r < cnt; r += RT) {
      const float* xrow = text + (size_t)(b * NTXT + i0 + r) * DIM;
      float x[4];
      float s = 0.f;
#pragma unroll
      for (int u = 0; u < 4; u++) { x[u] = xrow[tid + 256 * u]; s += x[u]; }
      red[tid] = s; __syncthreads();
      for (int st = 128; st > 0; st >>= 1) {
        if (tid < st) red[tid] += red[tid + st];
        __syncthreads();
      }
      const float mu = red[0] * (1.0f / DIM); __syncthreads();
      float vs = 0.f;
#pragma unroll
      for (int u = 0; u < 4; u++) { float d = x[u] - mu; vs += d * d; }
      red[tid] = vs; __syncthreads();
      for (int st = 128; st > 0; st >>= 1) {
        if (tid < st) red[tid] += red[tid + st];
        __syncthreads();
      }
      const float rstd = rsqrtf(red[0] * (1.0f / DIM) + 1e-5f); __syncthreads();
      float* trow = tn + (size_t)(b * RMAX + r) * DIM;
#pragma unroll
      for (int u = 0; u < 4; u++) {
        const int c = tid + 256 * u;
        trow[c] = (x[u] - mu) * rstd * gamma[c] + beta[c];
      }
      __syncthreads();
    }
  } else {
    // ---- vbar partial matvec (c-chunked); ibar chunk reduced from ipart ----
    const int j = idx - 64;             // 0..63
    const int b = j >> 5, et = (j >> 3) & 3, cc = j & 7;
    const int e = et * 256 + tid;
    const int c0 = cc * 128;
    if (tid < 128) {
      float s = 0.f;
      for (int p = 0; p < 128; p++)
        s += ipart[(size_t)(b * 128 + p) * DIM + c0 + tid];
      red[tid] = s * (1.0f / (float)TM);
    }
    __syncthreads();
    float s = 0.f;
    for (int c = 0; c < 128; c++)
      s += red[c] * Wkv[(size_t)(c0 + c) * KVW + DIM + e];
    atomicAdd(&vbar[b * DIM + e], s);
  }
}

// ---------------------------------------------------------------------------
// K3: blocks 0..255  : f16 MFMA GEMM kv16 = img16 @ WkvT^T
//                      (m97 structure: 128x128 tile, BK=32, 4 waves,
//                       global_load_lds width-16 staging, XCD swizzle)
//     blocks 256..319: qproj partials (c-chunked, r-inner FMA, atomics)
//     blocks 320..383: obar partials  (c-chunked, atomics)
// ---------------------------------------------------------------------------
__global__ __launch_bounds__(256) void k3_gemm_qproj_obar(
    const _Float16* __restrict__ img16, const _Float16* __restrict__ WkvT,
    const float* __restrict__ Wq, const float* __restrict__ Wo,
    const float* __restrict__ tn, const float* __restrict__ vbar,
    const int* __restrict__ seg, _Float16* __restrict__ kv16,
    float* __restrict__ qbuf, float* __restrict__ obar) {
  __shared__ __align__(16) char smem[16384];
  const int idx = blockIdx.x;
  const int tid = threadIdx.x;
  if (idx < 256) {
    // ---- GEMM: C tile 128x128, BK=32, 4 waves each 64x64 ----
    _Float16* As = (_Float16*)smem;          // 128*32 f16 = 8 KB
    _Float16* Bs = As + 128 * 32;            // 8 KB
    const int swz = (idx & 7) * 32 + (idx >> 3);   // bijective XCD swizzle
    const int lane = tid & 63, wid = tid >> 6;     // 4 waves
    const int wm = wid & 1, wn = wid >> 1;         // 2x2 wave grid
    const int row0 = (swz >> 4) * 128, col0 = (swz & 15) * 128;
    const int frow = lane & 15, fq = lane >> 4;
    const int srow = lane >> 2, skc = (lane & 3) * 8;  // staging geometry
    f32x4 acc[4][4] = {};
    for (int k0 = 0; k0 < DIM; k0 += 32) {
      __syncthreads();   // all waves done reading LDS from previous step
#pragma unroll
      for (int i = 0; i < 2; i++) {
        const int ci = wid * 2 + i;          // 8 chunks of 16 rows
        const int r = ci * 16 + srow;
        GLOAD_LDS16(img16 + (size_t)(row0 + r) * DIM + k0 + skc,
                    As + ci * 512);
        GLOAD_LDS16(WkvT + (size_t)(col0 + r) * DIM + k0 + skc,
                    Bs + ci * 512);
      }
      __syncthreads();   // drains vmcnt(0) -> LDS tiles ready
      f16x8 af[4], bf[4];
#pragma unroll
      for (int mt = 0; mt < 4; mt++)
        af[mt] = *reinterpret_cast<const f16x8*>(
            As + (wm * 64 + mt * 16 + frow) * 32 + fq * 8);
#pragma unroll
      for (int nt = 0; nt < 4; nt++)
        bf[nt] = *reinterpret_cast<const f16x8*>(
            Bs + (wn * 64 + nt * 16 + frow) * 32 + fq * 8);
#pragma unroll
      for (int mt = 0; mt < 4; mt++)
#pragma unroll
        for (int nt = 0; nt < 4; nt++)
          acc[mt][nt] = __builtin_amdgcn_mfma_f32_16x16x32_f16(
              af[mt], bf[nt], acc[mt][nt], 0, 0, 0);
    }
#pragma unroll
    for (int mt = 0; mt < 4; mt++)
#pragma unroll
      for (int nt = 0; nt < 4; nt++) {
        const int col = col0 + wn * 64 + nt * 16 + frow;
#pragma unroll
        for (int r = 0; r < 4; r++) {
          const int row = row0 + wm * 64 + mt * 16 + fq * 4 + r;
          kv16[(size_t)row * KVW + col] = (_Float16)acc[mt][nt][r];
        }
      }
  } else if (idx < 320) {
    // ---- qproj: q[r, n0:n0+128] += tn[r, c0:c0+256] @ Wq[c0:c0+256, n] ----
    float* tn_s = (float*)smem;              // 8 rows x 256 c = 8 KB
    const int j = idx - 256;                 // 0..63
    const int b = j >> 5, nt = (j >> 2) & 7, cc = j & 3;
    const int n0 = nt * 128, c0 = cc * 256;
    const int n = tid & 127, cs = tid >> 7;  // 2 c-subchunks of 128
    const int cnt = min(seg[b * 2 + 1], RMAX);
    for (int r0 = 0; r0 < cnt; r0 += 8) {
      const int rows = min(8, cnt - r0);
      for (int i = tid; i < 8 * 256; i += 256) {
        const int r = i >> 8, c = i & 255;
        tn_s[i] = (r < rows) ? tn[(size_t)(b * RMAX + r0 + r) * DIM + c0 + c]
                             : 0.f;
      }
      __syncthreads();
      float acc[8] = {};
      for (int ci = 0; ci < 128; ci++) {
        const int c = cs * 128 + ci;
        const float w = Wq[(size_t)(c0 + c) * DIM + n0 + n];
#pragma unroll
        for (int rr = 0; rr < 8; rr++) acc[rr] += tn_s[rr * 256 + c] * w;
      }
      for (int rr = 0; rr < rows; rr++)
        atomicAdd(&qbuf[(size_t)(b * RMAX + r0 + rr) * DIM + n0 + n], acc[rr]);
      __syncthreads();
    }
  } else {
    // ---- obar: obar[b,e] += vbar[b, c0:c0+128] @ Wo[c0:c0+128, e] ----
    float* vb_s = (float*)smem;              // 128 f32
    const int j = idx - 320;                 // 0..63
    const int b = j >> 5, et = (j >> 3) & 3, cc = j & 7;
    const int e = et * 256 + tid;
    const int c0 = cc * 128;
    if (tid < 128) vb_s[tid] = vbar[b * DIM + c0 + tid];
    __syncthreads();
    float s = 0.f;
    for (int c = 0; c < 128; c++)
      s += vb_s[c] * Wo[(size_t)(c0 + c) * DIM + e];
    atomicAdd(&obar[b * DIM + e], s);
  }
}

// ---------------------------------------------------------------------------
// K4: blocks 0..4095    : fill (zero / obar / fallback)
//     blocks 4096..5119 : attnh (q from qbuf, scores, softmax, PV -> oacc)
// ---------------------------------------------------------------------------
__global__ __launch_bounds__(256) void k4_fill_attn(
    const float* __restrict__ text, const _Float16* __restrict__ kv16,
    const float* __restrict__ Wq, const float* __restrict__ Wo,
    const float* __restrict__ gamma, const float* __restrict__ beta,
    const int* __restrict__ tt, const int* __restrict__ seg,
    const float* __restrict__ obar, const float* __restrict__ qbuf,
    float* __restrict__ oacc, float* __restrict__ out) {
  __shared__ float red[256];
  __shared__ float pbuf[256];
  const int idx = blockIdx.x;
  const int tid = threadIdx.x;
  if (idx < BATCH * NTXT) {
    const int b = idx >> 11;
    const int i = idx & (NTXT - 1);
    const int t = tt[b * NTXT + i];
    float* orow = out + (size_t)(b * NTXT + i) * DIM;
    if (t == 0) {
      for (int c = tid; c < DIM; c += 256) orow[c] = 0.f;
      return;
    }
    if (t > TMED) {
      const float* ob = obar + b * DIM;
      for (int c = tid; c < DIM; c += 256) orow[c] = ob[c];
      return;
    }
    if (i - seg[b * 2] < RMAX) return;
    // ---- slow fallback (unreachable for realistic data) ----
    __shared__ float tns[DIM];
    __shared__ float qrow[DIM];
    __shared__ float oaccs[DIM];
    const float* xrow = text + (size_t)(b * NTXT + i) * DIM;
    float x[4];
    float s = 0.f;
#pragma unroll
    for (int u = 0; u < 4; u++) { x[u] = xrow[tid + 256 * u]; s += x[u]; }
    red[tid] = s; __syncthreads();
    for (int st = 128; st > 0; st >>= 1) {
      if (tid < st) red[tid] += red[tid + st];
      __syncthreads();
    }
    const float mu = red[0] * (1.0f / DIM); __syncthreads();
    float vs = 0.f;
#pragma unroll
    for (int u = 0; u < 4; u++) { float d = x[u] - mu; vs += d * d; }
    red[tid] = vs; __syncthreads();
    for (int st = 128; st > 0; st >>= 1) {
      if (tid < st) red[tid] += red[tid + st];
      __syncthreads();
    }
    const float rstd = rsqrtf(red[0] * (1.0f / DIM) + 1e-5f); __syncthreads();
#pragma unroll
    for (int u = 0; u < 4; u++) {
      const int c = tid + 256 * u;
      tns[c] = (x[u] - mu) * rstd * gamma[c] + beta[c];
    }
    __syncthreads();
    {
      float qa[4] = {0.f, 0.f, 0.f, 0.f};
      for (int c = 0; c < DIM; c++) {
        const float tv = tns[c];
        const float* w = Wq + (size_t)c * DIM + tid;
#pragma unroll
        for (int u = 0; u < 4; u++) qa[u] += tv * w[256 * u];
      }
#pragma unroll
      for (int u = 0; u < 4; u++) qrow[tid + 256 * u] = qa[u];
    }
    __syncthreads();
    const size_t kvrow0 = (size_t)(b * TM + (t - 1) * MMED) * KVW;
    const int d0 = tid & 63, g = tid >> 6;
    for (int h = 0; h < NH; h++) {
      const _Float16* krow = kv16 + kvrow0 + (size_t)tid * KVW + h * DHD;
      float sc = 0.f;
#pragma unroll
      for (int d = 0; d < DHD; d++) sc += qrow[h * DHD + d] * (float)krow[d];
      sc *= 0.125f;
      red[tid] = sc; __syncthreads();
      for (int st = 128; st > 0; st >>= 1) {
        if (tid < st) red[tid] = fmaxf(red[tid], red[tid + st]);
        __syncthreads();
      }
      const float mx = red[0]; __syncthreads();
      const float e = __expf(sc - mx);
      red[tid] = e; __syncthreads();
      for (int st = 128; st > 0; st >>= 1) {
        if (tid < st) red[tid] += red[tid + st];
        __syncthreads();
      }
      const float inv = 1.0f / red[0]; __syncthreads();
      pbuf[tid] = e * inv; __syncthreads();
      const _Float16* vbase = kv16 + kvrow0 + (size_t)(g * 64) * KVW + DIM + h * DHD + d0;
      float a = 0.f;
#pragma unroll 8
      for (int jj = 0; jj < 64; jj++) a += pbuf[g * 64 + jj] * (float)vbase[(size_t)jj * KVW];
      red[tid] = a; __syncthreads();
      if (tid < 64)
        oaccs[h * DHD + tid] = red[tid] + red[64 + tid] + red[128 + tid] + red[192 + tid];
      __syncthreads();
    }
    float oa[4] = {0.f, 0.f, 0.f, 0.f};
    for (int c = 0; c < DIM; c++) {
      const float ov = oaccs[c];
      const float* w = Wo + (size_t)c * DIM + tid;
#pragma unroll
      for (int u = 0; u < 4; u++) oa[u] += ov * w[256 * u];
    }
#pragma unroll
    for (int u = 0; u < 4; u++) orow[tid + 256 * u] = oa[u];
  } else {
    // ---- attnh ----
    __shared__ float qs[DHD];
    const int j = idx - BATCH * NTXT;       // 0..1023
    const int h = j & 15, rt = (j >> 4) & 31, b = j >> 9;
    const int i0 = seg[b * 2];
    const int cnt = min(seg[b * 2 + 1], RMAX);
    const int d0 = tid & 63, g = tid >> 6;
    for (int r = rt; r < cnt; r += RT) {
      const int i = i0 + r;
      const int t = tt[b * NTXT + i];       // in [1, TMED]
      if (tid < 64) qs[tid] = qbuf[(size_t)(b * RMAX + r) * DIM + h * DHD + tid];
      __syncthreads();
      const size_t kvrow0 = (size_t)(b * TM + (t - 1) * MMED) * KVW;
      const _Float16* krow = kv16 + kvrow0 + (size_t)tid * KVW + h * DHD;
      float sc = 0.f;
#pragma unroll
      for (int d = 0; d < DHD; d += 8) {
        const f16x8 kk = *reinterpret_cast<const f16x8*>(krow + d);
#pragma unroll
        for (int u = 0; u < 8; u++) sc += qs[d + u] * (float)kk[u];
      }
      sc *= 0.125f;
      red[tid] = sc; __syncthreads();
      for (int st = 128; st > 0; st >>= 1) {
        if (tid < st) red[tid] = fmaxf(red[tid], red[tid + st]);
        __syncthreads();
      }
      const float mx = red[0]; __syncthreads();
      const float e = __expf(sc - mx);
      red[tid] = e; __syncthreads();
      for (int st = 128; st > 0; st >>= 1) {
        if (tid < st) red[tid] += red[tid + st];
        __syncthreads();
      }
      const float inv = 1.0f / red[0]; __syncthreads();
      pbuf[tid] = e * inv; __syncthreads();
      const _Float16* vbase = kv16 + kvrow0 + (size_t)(g * 64) * KVW + DIM + h * DHD + d0;
      float a = 0.f;
#pragma unroll 8
      for (int jj = 0; jj < 64; jj++) a += pbuf[g * 64 + jj] * (float)vbase[(size_t)jj * KVW];
      red[tid] = a; __syncthreads();
      if (tid < 64)
        oacc[(size_t)(b * RMAX + r) * DIM + h * DHD + tid] =
            red[tid] + red[64 + tid] + red[128 + tid] + red[192 + tid];
      __syncthreads();
    }
  }
}

// ---------------------------------------------------------------------------
// K5: output projection for real rows. grid (16, RT, BATCH)
// ---------------------------------------------------------------------------
__global__ __launch_bounds__(256) void k5_oproj(
    const float* __restrict__ oacc, const float* __restrict__ Wo,
    const int* __restrict__ seg, float* __restrict__ out) {
  const int ct = blockIdx.x;
  const int rt = blockIdx.y;
  const int b = blockIdx.z;
  const int i0 = seg[b * 2];
  const int cnt = min(seg[b * 2 + 1], RMAX);
  const int tid = threadIdx.x;
  const int d0 = tid & 63, g = tid >> 6;
  __shared__ float op[4][64];
  for (int r = rt; r < cnt; r += RT) {
    const float* arow = oacc + (size_t)(b * RMAX + r) * DIM;
    const float* wo = Wo + (size_t)(g * 256) * DIM + ct * 64 + d0;
    float s = 0.f;
    for (int c = 0; c < 256; c++) s += arow[g * 256 + c] * wo[(size_t)c * DIM];
    op[g][d0] = s; __syncthreads();
    if (tid < 64)
      out[(size_t)(b * NTXT + i0 + r) * DIM + ct * 64 + tid] =
          op[0][tid] + op[1][tid] + op[2][tid] + op[3][tid];
    __syncthreads();
  }
}

// ---------------------------------------------------------------------------
extern "C" void kernel_launch(void* const* d_in, const int* in_sizes, int n_in,
                              void* d_out, int out_size, void* d_ws, size_t ws_size,
                              hipStream_t stream) {
  const float* text  = (const float*)d_in[0];
  const float* image = (const float*)d_in[1];
  const int*   loc   = (const int*)d_in[2];
  const float* Wq    = (const float*)d_in[3];
  const float* Wkv   = (const float*)d_in[4];
  const float* Wo    = (const float*)d_in[5];
  const float* gamma = (const float*)d_in[6];
  const float* beta  = (const float*)d_in[7];
  float* out = (float*)d_out;

  // ws layout: kv16 8MB | WkvT 4MB (aliased by oacc 2MB after k3) |
  //            img16 4MB | tn 2MB | [memset: qbuf 2MB | vbar | obar]
  //            | tt | seg | ipart 1MB   (~21.3 MB total)
  _Float16* kv16  = (_Float16*)d_ws;
  _Float16* WkvT  = kv16 + (size_t)BATCH * TM * KVW;
  float*    oacc  = (float*)WkvT;                      // alias: k4/k5 > k3 use
  _Float16* img16 = WkvT + (size_t)KVW * DIM;
  float*    tn    = (float*)(img16 + (size_t)BATCH * TM * DIM);
  float*    qbuf  = tn + (size_t)BATCH * RMAX * DIM;
  float*    vbar  = qbuf + (size_t)BATCH * RMAX * DIM;
  float*    obar  = vbar + BATCH * DIM;
  int*      tt    = (int*)(obar + BATCH * DIM);
  int*      seg   = tt + BATCH * NTXT;
  float*    ipart = (float*)(seg + 8);                 // 256*1024 f32 = 1MB

  // zero qbuf + vbar + obar in one contiguous memset (ipart needs no zeroing)
  hipMemsetAsync(qbuf, 0,
                 ((size_t)BATCH * RMAX * DIM + 2 * BATCH * DIM) * sizeof(float),
                 stream);
  k1_scan_cvt_tr<<<BATCH + 256 + 512, 1024, 0, stream>>>(
      loc, image, Wkv, tt, seg, ipart, img16, WkvT);
  k2_prep<<<128, 256, 0, stream>>>(Wkv, text, gamma, beta, seg, ipart, tn, vbar);
  k3_gemm_qproj_obar<<<384, 256, 0, stream>>>(img16, WkvT, Wq, Wo, tn, vbar,
                                              seg, kv16, qbuf, obar);
  k4_fill_attn<<<BATCH * NTXT + NH * RT * BATCH, 256, 0, stream>>>(
      text, kv16, Wq, Wo, gamma, beta, tt, seg, obar, qbuf, oacc, out);
  k5_oproj<<<dim3(16, RT, BATCH), 256, 0, stream>>>(oacc, Wo, seg, out);
}

// Round 2
// 152.960 us; speedup vs baseline: 1.1057x; 1.1057x over previous
//
#include <hip/hip_runtime.h>

// Problem constants (setup_inputs is fixed)
#define BATCH 2
#define NTXT  2048
#define TMED  4
#define MMED  256
#define TM    (TMED * MMED)      // 1024 kv rows per batch
#define DIM   1024
#define NH    16
#define DHD   64
#define KVW   2048               // k|v concatenated width
#define RMAX  256                // max real rows per batch handled by fast path
#define RT    32                 // row-tile parallelism for heavy-path kernels

typedef _Float16 f16x8 __attribute__((ext_vector_type(8)));
typedef float    f32x4 __attribute__((ext_vector_type(4)));

// ---------------------------------------------------------------------------
// K1: blocks 0..1   : inclusive scan of locations -> txt_time + segment
//                     (segment bounds via ballot, NOT serialized LDS atomics)
//     blocks 2..257 : img16 = (f16)image + per-block column partial sums
//                     ipart[b*128+rt][c] (256 blocks -> full-chip BW)
//     blocks 258..769: Wkv (K x N f32) -> WkvT (N x K f16) transpose
// ---------------------------------------------------------------------------
__global__ __launch_bounds__(1024) void k1_scan_cvt_tr(
    const int* __restrict__ loc, const float* __restrict__ image,
    const float* __restrict__ Wkv, int* __restrict__ tt, int* __restrict__ seg,
    float* __restrict__ ipart, _Float16* __restrict__ img16,
    _Float16* __restrict__ WkvT) {
  __shared__ int buf[NTXT];
  __shared__ float tile[64][65];
  __shared__ int wmin[2][16];
  const int idx = blockIdx.x;
  const int tid = threadIdx.x;
  if (idx < BATCH) {
    // ---- scan ----
    const int b = idx;
    buf[tid]        = loc[b * NTXT + tid];
    buf[tid + 1024] = loc[b * NTXT + tid + 1024];
    __syncthreads();
    for (int off = 1; off < NTXT; off <<= 1) {
      int a0 = (tid >= off) ? buf[tid - off] : 0;
      int a1 = buf[tid + 1024 - off];
      __syncthreads();
      buf[tid] += a0;
      buf[tid + 1024] += a1;
      __syncthreads();
    }
    const int v0 = buf[tid], v1 = buf[tid + 1024];
    tt[b * NTXT + tid]        = v0;
    tt[b * NTXT + tid + 1024] = v1;
    // first index with tt>=1 (start) and tt>=5 (end) via per-wave ballots;
    // within a wave, half0 indices (tid) are always < half1 (tid+1024).
    const int lane = tid & 63, w = tid >> 6;
    const unsigned long long b1a = __ballot(v0 >= 1);
    const unsigned long long b1b = __ballot(v1 >= 1);
    const unsigned long long b5a = __ballot(v0 >= 5);
    const unsigned long long b5b = __ballot(v1 >= 5);
    if (lane == 0) {
      int s1 = NTXT, s5 = NTXT;
      if (b1a)      s1 = w * 64 + (__ffsll(b1a) - 1);
      else if (b1b) s1 = 1024 + w * 64 + (__ffsll(b1b) - 1);
      if (b5a)      s5 = w * 64 + (__ffsll(b5a) - 1);
      else if (b5b) s5 = 1024 + w * 64 + (__ffsll(b5b) - 1);
      wmin[0][w] = s1;
      wmin[1][w] = s5;
    }
    __syncthreads();
    if (tid == 0) {
      int s = NTXT, e = NTXT;
#pragma unroll
      for (int i = 0; i < 16; i++) {
        s = min(s, wmin[0][i]);
        e = min(e, wmin[1][i]);
      }
      seg[b * 2]     = s;
      seg[b * 2 + 1] = e - s;
    }
  } else if (idx < BATCH + 256) {
    // ---- image convert + partial column sums ----
    const int j = idx - BATCH;           // 0..255
    const int b = j >> 7, rt = j & 127;  // 128 row-tiles of 8 per batch
    const size_t base = (size_t)(b * TM + rt * 8) * DIM + tid;
    const float* p = image + base;
    _Float16* q = img16 + base;
    float s = 0.f;
#pragma unroll
    for (int r = 0; r < 8; r++) {
      const float v = p[(size_t)r * DIM];
      s += v;
      q[(size_t)r * DIM] = (_Float16)v;
    }
    ipart[(size_t)(b * 128 + rt) * DIM + tid] = s;
  } else {
    // ---- transpose+convert Wkv (64x64 tiles, 1024 threads) ----
    const int j2 = idx - BATCH - 256;    // 0..511
    const int k0 = (j2 & 15) * 64, n0 = (j2 >> 4) * 64;
    const int r = tid >> 4, c4 = (tid & 15) * 4;
    const float4 v = *reinterpret_cast<const float4*>(
        Wkv + (size_t)(k0 + r) * KVW + n0 + c4);
    tile[r][c4 + 0] = v.x; tile[r][c4 + 1] = v.y;
    tile[r][c4 + 2] = v.z; tile[r][c4 + 3] = v.w;
    __syncthreads();
    if (tid < 512) {
      const int n = tid >> 3, kc = (tid & 7) * 8;
      f16x8 h;
#pragma unroll
      for (int u = 0; u < 8; u++) h[u] = (_Float16)tile[kc + u][n];
      *reinterpret_cast<f16x8*>(WkvT + (size_t)(n0 + n) * DIM + k0 + kc) = h;
    }
  }
}

// ---------------------------------------------------------------------------
// K2: blocks 0..63  : LayerNorm of real rows -> tn
//     blocks 64..127: vbar[b,e] += (reduce ipart -> ibar chunk) @ Wkv_v
// ---------------------------------------------------------------------------
__global__ __launch_bounds__(256) void k2_prep(
    const float* __restrict__ Wkv, const float* __restrict__ text,
    const float* __restrict__ gamma, const float* __restrict__ beta,
    const int* __restrict__ seg, const float* __restrict__ ipart,
    float* __restrict__ tn, float* __restrict__ vbar) {
  __shared__ float red[256];
  const int idx = blockIdx.x;
  const int tid = threadIdx.x;
  if (idx < 64) {
    // ---- LayerNorm of real rows ----
    const int b = idx >> 5, rt = idx & 31;
    const int i0 = seg[b * 2];
    const int cnt = min(seg[b * 2 + 1], RMAX);
    for (int r = rt; r < cnt; r += RT) {
      const float* xrow = text + (size_t)(b * NTXT + i0 + r) * DIM;
      float x[4];
      float s = 0.f;
#pragma unroll
      for (int u = 0; u < 4; u++) { x[u] = xrow[tid + 256 * u]; s += x[u]; }
      red[tid] = s; __syncthreads();
      for (int st = 128; st > 0; st >>= 1) {
        if (tid < st) red[tid] += red[tid + st];
        __syncthreads();
      }
      const float mu = red[0] * (1.0f / DIM); __syncthreads();
      float vs = 0.f;
#pragma unroll
      for (int u = 0; u < 4; u++) { float d = x[u] - mu; vs += d * d; }
      red[tid] = vs; __syncthreads();
      for (int st = 128; st > 0; st >>= 1) {
        if (tid < st) red[tid] += red[tid + st];
        __syncthreads();
      }
      const float rstd = rsqrtf(red[0] * (1.0f / DIM) + 1e-5f); __syncthreads();
      float* trow = tn + (size_t)(b * RMAX + r) * DIM;
#pragma unroll
      for (int u = 0; u < 4; u++) {
        const int c = tid + 256 * u;
        trow[c] = (x[u] - mu) * rstd * gamma[c] + beta[c];
      }
      __syncthreads();
    }
  } else {
    // ---- vbar partial matvec (c-chunked); ibar chunk reduced from ipart ----
    const int j = idx - 64;             // 0..63
    const int b = j >> 5, et = (j >> 3) & 3, cc = j & 7;
    const int e = et * 256 + tid;
    const int c0 = cc * 128;
    if (tid < 128) {
      float s = 0.f;
      for (int p = 0; p < 128; p++)
        s += ipart[(size_t)(b * 128 + p) * DIM + c0 + tid];
      red[tid] = s * (1.0f / (float)TM);
    }
    __syncthreads();
    float s = 0.f;
    for (int c = 0; c < 128; c++)
      s += red[c] * Wkv[(size_t)(c0 + c) * KVW + DIM + e];
    atomicAdd(&vbar[b * DIM + e], s);
  }
}

// ---------------------------------------------------------------------------
// K3: blocks 0..255  : f16 MFMA GEMM kv16 = img16 @ WkvT^T (128x128, BK=32,
//                      8 waves, reg-staged LDS — proven round-0 structure)
//     blocks 256..319: qproj partials (c-chunked, r-inner FMA, atomics)
//     blocks 320..351: obar partials  (c-chunked, atomics)
// ---------------------------------------------------------------------------
__global__ __launch_bounds__(512) void k3_gemm_qproj_obar(
    const _Float16* __restrict__ img16, const _Float16* __restrict__ WkvT,
    const float* __restrict__ Wq, const float* __restrict__ Wo,
    const float* __restrict__ tn, const float* __restrict__ vbar,
    const int* __restrict__ seg, _Float16* __restrict__ kv16,
    float* __restrict__ qbuf, float* __restrict__ obar) {
  __shared__ __align__(16) char smem[16384];
  const int idx = blockIdx.x;
  const int tid = threadIdx.x;
  if (idx < 256) {
    // ---- GEMM ----
    _Float16* As = (_Float16*)smem;          // 128*32 f16 = 8 KB
    _Float16* Bs = As + 128 * 32;            // 8 KB
    const int lane = tid & 63, wid = tid >> 6;
    const int wm = wid & 3, wn = wid >> 2;
    const int row0 = (idx >> 4) * 128, col0 = (idx & 15) * 128;
    const int srow = tid >> 2, skc = (tid & 3) * 8;
    const int frow = lane & 15, fq = lane >> 4;
    f32x4 acc[2][4] = {};
    for (int k0 = 0; k0 < DIM; k0 += 32) {
      const f16x8 av = *reinterpret_cast<const f16x8*>(
          img16 + (size_t)(row0 + srow) * DIM + k0 + skc);
      const f16x8 bv = *reinterpret_cast<const f16x8*>(
          WkvT + (size_t)(col0 + srow) * DIM + k0 + skc);
      __syncthreads();
      *reinterpret_cast<f16x8*>(As + tid * 8) = av;
      *reinterpret_cast<f16x8*>(Bs + tid * 8) = bv;
      __syncthreads();
      f16x8 af[2], bf[4];
#pragma unroll
      for (int mt = 0; mt < 2; mt++)
        af[mt] = *reinterpret_cast<const f16x8*>(
            As + (wm * 32 + mt * 16 + frow) * 32 + fq * 8);
#pragma unroll
      for (int nt = 0; nt < 4; nt++)
        bf[nt] = *reinterpret_cast<const f16x8*>(
            Bs + (wn * 64 + nt * 16 + frow) * 32 + fq * 8);
#pragma unroll
      for (int mt = 0; mt < 2; mt++)
#pragma unroll
        for (int nt = 0; nt < 4; nt++)
          acc[mt][nt] = __builtin_amdgcn_mfma_f32_16x16x32_f16(
              af[mt], bf[nt], acc[mt][nt], 0, 0, 0);
    }
#pragma unroll
    for (int mt = 0; mt < 2; mt++)
#pragma unroll
      for (int nt = 0; nt < 4; nt++) {
        const int col = col0 + wn * 64 + nt * 16 + frow;
#pragma unroll
        for (int r = 0; r < 4; r++) {
          const int row = row0 + wm * 32 + mt * 16 + fq * 4 + r;
          kv16[(size_t)row * KVW + col] = (_Float16)acc[mt][nt][r];
        }
      }
  } else if (idx < 320) {
    // ---- qproj: q[r, n0:n0+128] += tn[r, c0:c0+256] @ Wq[c0:c0+256, n] ----
    float* tn_s = (float*)smem;              // 8 rows x 256 c = 8 KB
    const int j = idx - 256;                 // 0..63
    const int b = j >> 5, nt = (j >> 2) & 7, cc = j & 3;
    const int n0 = nt * 128, c0 = cc * 256;
    const int n = tid & 127, cs = tid >> 7;  // 4 c-subchunks of 64
    const int cnt = min(seg[b * 2 + 1], RMAX);
    for (int r0 = 0; r0 < cnt; r0 += 8) {
      const int rows = min(8, cnt - r0);
      for (int i = tid; i < 8 * 256; i += 512) {
        const int r = i >> 8, c = i & 255;
        tn_s[i] = (r < rows) ? tn[(size_t)(b * RMAX + r0 + r) * DIM + c0 + c]
                             : 0.f;
      }
      __syncthreads();
      float acc[8] = {};
      for (int ci = 0; ci < 64; ci++) {
        const int c = cs * 64 + ci;
        const float w = Wq[(size_t)(c0 + c) * DIM + n0 + n];
#pragma unroll
        for (int rr = 0; rr < 8; rr++) acc[rr] += tn_s[rr * 256 + c] * w;
      }
      for (int rr = 0; rr < rows; rr++)
        atomicAdd(&qbuf[(size_t)(b * RMAX + r0 + rr) * DIM + n0 + n], acc[rr]);
      __syncthreads();
    }
  } else {
    // ---- obar: obar[b,e] += vbar[b, c0:c0+128] @ Wo[c0:c0+128, e] ----
    float* vb_s = (float*)smem;              // 128 f32
    const int j = idx - 320;                 // 0..31
    const int b = j >> 4, et = (j >> 3) & 1, cc = j & 7;
    const int e = et * 512 + tid;
    const int c0 = cc * 128;
    if (tid < 128) vb_s[tid] = vbar[b * DIM + c0 + tid];
    __syncthreads();
    float s = 0.f;
    for (int c = 0; c < 128; c++)
      s += vb_s[c] * Wo[(size_t)(c0 + c) * DIM + e];
    atomicAdd(&obar[b * DIM + e], s);
  }
}

// ---------------------------------------------------------------------------
// K4: blocks 0..4095    : fill (zero / obar / fallback)
//     blocks 4096..5119 : attnh (q from qbuf, scores, softmax, PV -> oacc)
// ---------------------------------------------------------------------------
__global__ __launch_bounds__(256) void k4_fill_attn(
    const float* __restrict__ text, const _Float16* __restrict__ kv16,
    const float* __restrict__ Wq, const float* __restrict__ Wo,
    const float* __restrict__ gamma, const float* __restrict__ beta,
    const int* __restrict__ tt, const int* __restrict__ seg,
    const float* __restrict__ obar, const float* __restrict__ qbuf,
    float* __restrict__ oacc, float* __restrict__ out) {
  __shared__ float red[256];
  __shared__ float pbuf[256];
  const int idx = blockIdx.x;
  const int tid = threadIdx.x;
  if (idx < BATCH * NTXT) {
    const int b = idx >> 11;
    const int i = idx & (NTXT - 1);
    const int t = tt[b * NTXT + i];
    float* orow = out + (size_t)(b * NTXT + i) * DIM;
    if (t == 0) {
      for (int c = tid; c < DIM; c += 256) orow[c] = 0.f;
      return;
    }
    if (t > TMED) {
      const float* ob = obar + b * DIM;
      for (int c = tid; c < DIM; c += 256) orow[c] = ob[c];
      return;
    }
    if (i - seg[b * 2] < RMAX) return;
    // ---- slow fallback (unreachable for realistic data) ----
    __shared__ float tns[DIM];
    __shared__ float qrow[DIM];
    __shared__ float oaccs[DIM];
    const float* xrow = text + (size_t)(b * NTXT + i) * DIM;
    float x[4];
    float s = 0.f;
#pragma unroll
    for (int u = 0; u < 4; u++) { x[u] = xrow[tid + 256 * u]; s += x[u]; }
    red[tid] = s; __syncthreads();
    for (int st = 128; st > 0; st >>= 1) {
      if (tid < st) red[tid] += red[tid + st];
      __syncthreads();
    }
    const float mu = red[0] * (1.0f / DIM); __syncthreads();
    float vs = 0.f;
#pragma unroll
    for (int u = 0; u < 4; u++) { float d = x[u] - mu; vs += d * d; }
    red[tid] = vs; __syncthreads();
    for (int st = 128; st > 0; st >>= 1) {
      if (tid < st) red[tid] += red[tid + st];
      __syncthreads();
    }
    const float rstd = rsqrtf(red[0] * (1.0f / DIM) + 1e-5f); __syncthreads();
#pragma unroll
    for (int u = 0; u < 4; u++) {
      const int c = tid + 256 * u;
      tns[c] = (x[u] - mu) * rstd * gamma[c] + beta[c];
    }
    __syncthreads();
    {
      float qa[4] = {0.f, 0.f, 0.f, 0.f};
      for (int c = 0; c < DIM; c++) {
        const float tv = tns[c];
        const float* w = Wq + (size_t)c * DIM + tid;
#pragma unroll
        for (int u = 0; u < 4; u++) qa[u] += tv * w[256 * u];
      }
#pragma unroll
      for (int u = 0; u < 4; u++) qrow[tid + 256 * u] = qa[u];
    }
    __syncthreads();
    const size_t kvrow0 = (size_t)(b * TM + (t - 1) * MMED) * KVW;
    const int d0 = tid & 63, g = tid >> 6;
    for (int h = 0; h < NH; h++) {
      const _Float16* krow = kv16 + kvrow0 + (size_t)tid * KVW + h * DHD;
      float sc = 0.f;
#pragma unroll
      for (int d = 0; d < DHD; d++) sc += qrow[h * DHD + d] * (float)krow[d];
      sc *= 0.125f;
      red[tid] = sc; __syncthreads();
      for (int st = 128; st > 0; st >>= 1) {
        if (tid < st) red[tid] = fmaxf(red[tid], red[tid + st]);
        __syncthreads();
      }
      const float mx = red[0]; __syncthreads();
      const float e = __expf(sc - mx);
      red[tid] = e; __syncthreads();
      for (int st = 128; st > 0; st >>= 1) {
        if (tid < st) red[tid] += red[tid + st];
        __syncthreads();
      }
      const float inv = 1.0f / red[0]; __syncthreads();
      pbuf[tid] = e * inv; __syncthreads();
      const _Float16* vbase = kv16 + kvrow0 + (size_t)(g * 64) * KVW + DIM + h * DHD + d0;
      float a = 0.f;
#pragma unroll 8
      for (int jj = 0; jj < 64; jj++) a += pbuf[g * 64 + jj] * (float)vbase[(size_t)jj * KVW];
      red[tid] = a; __syncthreads();
      if (tid < 64)
        oaccs[h * DHD + tid] = red[tid] + red[64 + tid] + red[128 + tid] + red[192 + tid];
      __syncthreads();
    }
    float oa[4] = {0.f, 0.f, 0.f, 0.f};
    for (int c = 0; c < DIM; c++) {
      const float ov = oaccs[c];
      const float* w = Wo + (size_t)c * DIM + tid;
#pragma unroll
      for (int u = 0; u < 4; u++) oa[u] += ov * w[256 * u];
    }
#pragma unroll
    for (int u = 0; u < 4; u++) orow[tid + 256 * u] = oa[u];
  } else {
    // ---- attnh ----
    __shared__ float qs[DHD];
    const int j = idx - BATCH * NTXT;       // 0..1023
    const int h = j & 15, rt = (j >> 4) & 31, b = j >> 9;
    const int i0 = seg[b * 2];
    const int cnt = min(seg[b * 2 + 1], RMAX);
    const int d0 = tid & 63, g = tid >> 6;
    for (int r = rt; r < cnt; r += RT) {
      const int i = i0 + r;
      const int t = tt[b * NTXT + i];       // in [1, TMED]
      if (tid < 64) qs[tid] = qbuf[(size_t)(b * RMAX + r) * DIM + h * DHD + tid];
      __syncthreads();
      const size_t kvrow0 = (size_t)(b * TM + (t - 1) * MMED) * KVW;
      const _Float16* krow = kv16 + kvrow0 + (size_t)tid * KVW + h * DHD;
      float sc = 0.f;
#pragma unroll
      for (int d = 0; d < DHD; d += 8) {
        const f16x8 kk = *reinterpret_cast<const f16x8*>(krow + d);
#pragma unroll
        for (int u = 0; u < 8; u++) sc += qs[d + u] * (float)kk[u];
      }
      sc *= 0.125f;
      red[tid] = sc; __syncthreads();
      for (int st = 128; st > 0; st >>= 1) {
        if (tid < st) red[tid] = fmaxf(red[tid], red[tid + st]);
        __syncthreads();
      }
      const float mx = red[0]; __syncthreads();
      const float e = __expf(sc - mx);
      red[tid] = e; __syncthreads();
      for (int st = 128; st > 0; st >>= 1) {
        if (tid < st) red[tid] += red[tid + st];
        __syncthreads();
      }
      const float inv = 1.0f / red[0]; __syncthreads();
      pbuf[tid] = e * inv; __syncthreads();
      const _Float16* vbase = kv16 + kvrow0 + (size_t)(g * 64) * KVW + DIM + h * DHD + d0;
      float a = 0.f;
#pragma unroll 8
      for (int jj = 0; jj < 64; jj++) a += pbuf[g * 64 + jj] * (float)vbase[(size_t)jj * KVW];
      red[tid] = a; __syncthreads();
      if (tid < 64)
        oacc[(size_t)(b * RMAX + r) * DIM + h * DHD + tid] =
            red[tid] + red[64 + tid] + red[128 + tid] + red[192 + tid];
      __syncthreads();
    }
  }
}

// ---------------------------------------------------------------------------
// K5: output projection for real rows. grid (16, RT, BATCH)
// ---------------------------------------------------------------------------
__global__ __launch_bounds__(256) void k5_oproj(
    const float* __restrict__ oacc, const float* __restrict__ Wo,
    const int* __restrict__ seg, float* __restrict__ out) {
  const int ct = blockIdx.x;
  const int rt = blockIdx.y;
  const int b = blockIdx.z;
  const int i0 = seg[b * 2];
  const int cnt = min(seg[b * 2 + 1], RMAX);
  const int tid = threadIdx.x;
  const int d0 = tid & 63, g = tid >> 6;
  __shared__ float op[4][64];
  for (int r = rt; r < cnt; r += RT) {
    const float* arow = oacc + (size_t)(b * RMAX + r) * DIM;
    const float* wo = Wo + (size_t)(g * 256) * DIM + ct * 64 + d0;
    float s = 0.f;
    for (int c = 0; c < 256; c++) s += arow[g * 256 + c] * wo[(size_t)c * DIM];
    op[g][d0] = s; __syncthreads();
    if (tid < 64)
      out[(size_t)(b * NTXT + i0 + r) * DIM + ct * 64 + tid] =
          op[0][tid] + op[1][tid] + op[2][tid] + op[3][tid];
    __syncthreads();
  }
}

// ---------------------------------------------------------------------------
extern "C" void kernel_launch(void* const* d_in, const int* in_sizes, int n_in,
                              void* d_out, int out_size, void* d_ws, size_t ws_size,
                              hipStream_t stream) {
  const float* text  = (const float*)d_in[0];
  const float* image = (const float*)d_in[1];
  const int*   loc   = (const int*)d_in[2];
  const float* Wq    = (const float*)d_in[3];
  const float* Wkv   = (const float*)d_in[4];
  const float* Wo    = (const float*)d_in[5];
  const float* gamma = (const float*)d_in[6];
  const float* beta  = (const float*)d_in[7];
  float* out = (float*)d_out;

  // ws layout: kv16 8MB | WkvT 4MB (aliased by oacc 2MB after k3) |
  //            img16 4MB | tn 2MB | [memset: qbuf 2MB | vbar | obar]
  //            | tt | seg | ipart 1MB   (~21.3 MB total)
  _Float16* kv16  = (_Float16*)d_ws;
  _Float16* WkvT  = kv16 + (size_t)BATCH * TM * KVW;
  float*    oacc  = (float*)WkvT;                      // alias: k4/k5 > k3 use
  _Float16* img16 = WkvT + (size_t)KVW * DIM;
  float*    tn    = (float*)(img16 + (size_t)BATCH * TM * DIM);
  float*    qbuf  = tn + (size_t)BATCH * RMAX * DIM;
  float*    vbar  = qbuf + (size_t)BATCH * RMAX * DIM;
  float*    obar  = vbar + BATCH * DIM;
  int*      tt    = (int*)(obar + BATCH * DIM);
  int*      seg   = tt + BATCH * NTXT;
  float*    ipart = (float*)(seg + 8);                 // 256*1024 f32 = 1MB

  // zero qbuf + vbar + obar in one contiguous memset (ipart needs no zeroing)
  hipMemsetAsync(qbuf, 0,
                 ((size_t)BATCH * RMAX * DIM + 2 * BATCH * DIM) * sizeof(float),
                 stream);
  k1_scan_cvt_tr<<<BATCH + 256 + 512, 1024, 0, stream>>>(
      loc, image, Wkv, tt, seg, ipart, img16, WkvT);
  k2_prep<<<128, 256, 0, stream>>>(Wkv, text, gamma, beta, seg, ipart, tn, vbar);
  k3_gemm_qproj_obar<<<352, 512, 0, stream>>>(img16, WkvT, Wq, Wo, tn, vbar,
                                              seg, kv16, qbuf, obar);
  k4_fill_attn<<<BATCH * NTXT + NH * RT * BATCH, 256, 0, stream>>>(
      text, kv16, Wq, Wo, gamma, beta, tt, seg, obar, qbuf, oacc, out);
  k5_oproj<<<dim3(16, RT, BATCH), 256, 0, stream>>>(oacc, Wo, seg, out);
}

// Round 3
// 152.607 us; speedup vs baseline: 1.1082x; 1.0023x over previous
//
#include <hip/hip_runtime.h>

// Problem constants (setup_inputs is fixed)
#define BATCH 2
#define NTXT  2048
#define TMED  4
#define MMED  256
#define TM    (TMED * MMED)      // 1024 kv rows per batch
#define DIM   1024
#define NH    16
#define DHD   64
#define KVW   2048               // k|v concatenated width
#define RMAX  256                // max real rows per batch handled by fast path
#define RT    32                 // row-tile parallelism for heavy-path kernels

typedef _Float16 f16x8 __attribute__((ext_vector_type(8)));
typedef float    f32x4 __attribute__((ext_vector_type(4)));

// ---------------------------------------------------------------------------
// K1: blocks 0..1   : inclusive scan of locations -> txt_time + segment
//                     (wave-shuffle scan: 2 barriers instead of 22)
//     blocks 2..257 : img16 = (f16)image + per-block column partial sums
//     blocks 258..769: Wkv (K x N f32) -> WkvT (N x K f16) transpose
//     blocks 770..785: zero qbuf|vbar|obar (absorbs the hipMemsetAsync)
// ---------------------------------------------------------------------------
__global__ __launch_bounds__(1024) void k1_scan_cvt_tr(
    const int* __restrict__ loc, const float* __restrict__ image,
    const float* __restrict__ Wkv, int* __restrict__ tt, int* __restrict__ seg,
    float* __restrict__ ipart, _Float16* __restrict__ img16,
    _Float16* __restrict__ WkvT, float* __restrict__ zbase) {
  __shared__ float tile[64][65];
  __shared__ int wtot[16];
  __shared__ int wmin[2][16];
  const int idx = blockIdx.x;
  const int tid = threadIdx.x;
  if (idx < BATCH) {
    // ---- scan: each thread owns 2 consecutive elements ----
    const int b = idx;
    const int lane = tid & 63, w = tid >> 6;
    const int e0 = tid * 2;
    const int a0 = loc[b * NTXT + e0], a1 = loc[b * NTXT + e0 + 1];
    const int p = a0 + a1;
    int incl = p;
#pragma unroll
    for (int off = 1; off < 64; off <<= 1) {
      const int t2 = __shfl_up(incl, off, 64);
      if (lane >= off) incl += t2;
    }
    if (lane == 63) wtot[w] = incl;
    __syncthreads();
    if (tid < 16) {
      const int v = wtot[tid];
      int inc2 = v;
#pragma unroll
      for (int off = 1; off < 16; off <<= 1) {
        const int t3 = __shfl_up(inc2, off, 64);
        if (tid >= off) inc2 += t3;
      }
      wtot[tid] = inc2 - v;          // exclusive prefix for wave tid
    }
    __syncthreads();
    const int base = wtot[w] + (incl - p);
    const int t0v = base + a0, t1v = t0v + a1;
    tt[b * NTXT + e0]     = t0v;
    tt[b * NTXT + e0 + 1] = t1v;
    // first index with tt>=1 and tt>=5 (tt nondecreasing)
    {
      const int c1 = (t1v >= 1) ? ((t0v >= 1) ? e0 : e0 + 1) : NTXT;
      const int c5 = (t1v >= 5) ? ((t0v >= 5) ? e0 : e0 + 1) : NTXT;
      const unsigned long long b1 = __ballot(t1v >= 1);
      const unsigned long long b5 = __ballot(t1v >= 5);
      int m1 = NTXT, m5 = NTXT;
      if (b1) m1 = __shfl(c1, __ffsll(b1) - 1, 64);
      if (b5) m5 = __shfl(c5, __ffsll(b5) - 1, 64);
      if (lane == 0) { wmin[0][w] = m1; wmin[1][w] = m5; }
    }
    __syncthreads();
    if (tid == 0) {
      int s = NTXT, e = NTXT;
#pragma unroll
      for (int i = 0; i < 16; i++) {
        s = min(s, wmin[0][i]);
        e = min(e, wmin[1][i]);
      }
      seg[b * 2]     = s;
      seg[b * 2 + 1] = e - s;
    }
  } else if (idx < BATCH + 256) {
    // ---- image convert + partial column sums ----
    const int j = idx - BATCH;           // 0..255
    const int b = j >> 7, rt = j & 127;  // 128 row-tiles of 8 per batch
    const size_t base = (size_t)(b * TM + rt * 8) * DIM + tid;
    const float* p = image + base;
    _Float16* q = img16 + base;
    float s = 0.f;
#pragma unroll
    for (int r = 0; r < 8; r++) {
      const float v = p[(size_t)r * DIM];
      s += v;
      q[(size_t)r * DIM] = (_Float16)v;
    }
    ipart[(size_t)(b * 128 + rt) * DIM + tid] = s;
  } else if (idx < BATCH + 256 + 512) {
    // ---- transpose+convert Wkv (64x64 tiles, 1024 threads) ----
    const int j2 = idx - BATCH - 256;    // 0..511
    const int k0 = (j2 & 15) * 64, n0 = (j2 >> 4) * 64;
    const int r = tid >> 4, c4 = (tid & 15) * 4;
    const float4 v = *reinterpret_cast<const float4*>(
        Wkv + (size_t)(k0 + r) * KVW + n0 + c4);
    tile[r][c4 + 0] = v.x; tile[r][c4 + 1] = v.y;
    tile[r][c4 + 2] = v.z; tile[r][c4 + 3] = v.w;
    __syncthreads();
    if (tid < 512) {
      const int n = tid >> 3, kc = (tid & 7) * 8;
      f16x8 h;
#pragma unroll
      for (int u = 0; u < 8; u++) h[u] = (_Float16)tile[kc + u][n];
      *reinterpret_cast<f16x8*>(WkvT + (size_t)(n0 + n) * DIM + k0 + kc) = h;
    }
  } else {
    // ---- zero qbuf + vbar + obar (528384 floats = 132096 float4) ----
    const int j = idx - (BATCH + 256 + 512);   // 0..15
    float4* z = reinterpret_cast<float4*>(zbase);
    const float4 zv = {0.f, 0.f, 0.f, 0.f};
    for (int i = j * 1024 + tid; i < 132096; i += 16 * 1024) z[i] = zv;
  }
}

// ---------------------------------------------------------------------------
// K2: blocks 0..63  : LayerNorm of real rows -> tn
//     blocks 64..127: vbar[b,e] += (reduce ipart -> ibar chunk) @ Wkv_v
//     blocks 128..129: zero out[] rows of the real segment (for k4's atomics)
// ---------------------------------------------------------------------------
__global__ __launch_bounds__(256) void k2_prep(
    const float* __restrict__ Wkv, const float* __restrict__ text,
    const float* __restrict__ gamma, const float* __restrict__ beta,
    const int* __restrict__ seg, const float* __restrict__ ipart,
    float* __restrict__ tn, float* __restrict__ vbar,
    float* __restrict__ out) {
  __shared__ float red[256];
  const int idx = blockIdx.x;
  const int tid = threadIdx.x;
  if (idx < 64) {
    // ---- LayerNorm of real rows ----
    const int b = idx >> 5, rt = idx & 31;
    const int i0 = seg[b * 2];
    const int cnt = min(seg[b * 2 + 1], RMAX);
    for (int r = rt; r < cnt; r += RT) {
      const float* xrow = text + (size_t)(b * NTXT + i0 + r) * DIM;
      float x[4];
      float s = 0.f;
#pragma unroll
      for (int u = 0; u < 4; u++) { x[u] = xrow[tid + 256 * u]; s += x[u]; }
      red[tid] = s; __syncthreads();
      for (int st = 128; st > 0; st >>= 1) {
        if (tid < st) red[tid] += red[tid + st];
        __syncthreads();
      }
      const float mu = red[0] * (1.0f / DIM); __syncthreads();
      float vs = 0.f;
#pragma unroll
      for (int u = 0; u < 4; u++) { float d = x[u] - mu; vs += d * d; }
      red[tid] = vs; __syncthreads();
      for (int st = 128; st > 0; st >>= 1) {
        if (tid < st) red[tid] += red[tid + st];
        __syncthreads();
      }
      const float rstd = rsqrtf(red[0] * (1.0f / DIM) + 1e-5f); __syncthreads();
      float* trow = tn + (size_t)(b * RMAX + r) * DIM;
#pragma unroll
      for (int u = 0; u < 4; u++) {
        const int c = tid + 256 * u;
        trow[c] = (x[u] - mu) * rstd * gamma[c] + beta[c];
      }
      __syncthreads();
    }
  } else if (idx < 128) {
    // ---- vbar partial matvec (c-chunked); ibar chunk reduced from ipart ----
    const int j = idx - 64;             // 0..63
    const int b = j >> 5, et = (j >> 3) & 3, cc = j & 7;
    const int e = et * 256 + tid;
    const int c0 = cc * 128;
    if (tid < 128) {
      float s = 0.f;
      for (int p = 0; p < 128; p++)
        s += ipart[(size_t)(b * 128 + p) * DIM + c0 + tid];
      red[tid] = s * (1.0f / (float)TM);
    }
    __syncthreads();
    float s = 0.f;
    for (int c = 0; c < 128; c++)
      s += red[c] * Wkv[(size_t)(c0 + c) * KVW + DIM + e];
    atomicAdd(&vbar[b * DIM + e], s);
  } else {
    // ---- zero real-segment output rows (k4 attnh atomicAdds into them) ----
    const int b = idx - 128;
    const int i0 = seg[b * 2];
    const int cnt = min(seg[b * 2 + 1], RMAX);
    for (int r = 0; r < cnt; r++) {
      float* orow = out + (size_t)(b * NTXT + i0 + r) * DIM;
      for (int c = tid; c < DIM; c += 256) orow[c] = 0.f;
    }
  }
}

// ---------------------------------------------------------------------------
// K3: blocks 0..255  : f16 MFMA GEMM kv16 = img16 @ WkvT^T (128x128, BK=64,
//                      8 waves, XOR-swizzled LDS, register prefetch pipeline;
//                      MFMA accumulation order identical to BK=32 version)
//     blocks 256..319: qproj partials (c-chunked, r-inner FMA, atomics)
//     blocks 320..351: obar partials  (c-chunked, atomics)
// ---------------------------------------------------------------------------
__global__ __launch_bounds__(512) void k3_gemm_qproj_obar(
    const _Float16* __restrict__ img16, const _Float16* __restrict__ WkvT,
    const float* __restrict__ Wq, const float* __restrict__ Wo,
    const float* __restrict__ tn, const float* __restrict__ vbar,
    const int* __restrict__ seg, _Float16* __restrict__ kv16,
    float* __restrict__ qbuf, float* __restrict__ obar) {
  __shared__ __align__(16) char smem[32768];
  const int idx = blockIdx.x;
  const int tid = threadIdx.x;
  if (idx < 256) {
    // ---- GEMM ----
    _Float16* As = (_Float16*)smem;          // 128*64 f16 = 16 KB
    _Float16* Bs = As + 128 * 64;            // 16 KB
    const int lane = tid & 63, wid = tid >> 6;
    const int wm = wid & 3, wn = wid >> 2;
    const int row0 = (idx >> 4) * 128, col0 = (idx & 15) * 128;
    const int srow = tid >> 3, skc = (tid & 7) * 8;   // 64 rows/pass, 2 passes
    const int frow = lane & 15, fq = lane >> 4;
    const int swk = skc ^ ((srow & 7) << 3);          // f16-index XOR swizzle
    f32x4 acc[2][4] = {};
    // prologue: prefetch k0 = 0
    f16x8 a0v = *reinterpret_cast<const f16x8*>(
        img16 + (size_t)(row0 + srow) * DIM + skc);
    f16x8 a1v = *reinterpret_cast<const f16x8*>(
        img16 + (size_t)(row0 + srow + 64) * DIM + skc);
    f16x8 b0v = *reinterpret_cast<const f16x8*>(
        WkvT + (size_t)(col0 + srow) * DIM + skc);
    f16x8 b1v = *reinterpret_cast<const f16x8*>(
        WkvT + (size_t)(col0 + srow + 64) * DIM + skc);
    for (int k0 = 0; k0 < DIM; k0 += 64) {
      __syncthreads();   // previous iteration's ds_reads done
      *reinterpret_cast<f16x8*>(As + srow * 64 + swk)        = a0v;
      *reinterpret_cast<f16x8*>(As + (srow + 64) * 64 + swk) = a1v;
      *reinterpret_cast<f16x8*>(Bs + srow * 64 + swk)        = b0v;
      *reinterpret_cast<f16x8*>(Bs + (srow + 64) * 64 + swk) = b1v;
      __syncthreads();
      if (k0 + 64 < DIM) {   // prefetch next slab; latency hides under MFMA
        a0v = *reinterpret_cast<const f16x8*>(
            img16 + (size_t)(row0 + srow) * DIM + k0 + 64 + skc);
        a1v = *reinterpret_cast<const f16x8*>(
            img16 + (size_t)(row0 + srow + 64) * DIM + k0 + 64 + skc);
        b0v = *reinterpret_cast<const f16x8*>(
            WkvT + (size_t)(col0 + srow) * DIM + k0 + 64 + skc);
        b1v = *reinterpret_cast<const f16x8*>(
            WkvT + (size_t)(col0 + srow + 64) * DIM + k0 + 64 + skc);
      }
      f16x8 af[2][2], bf[2][4];
#pragma unroll
      for (int kk = 0; kk < 2; kk++) {
#pragma unroll
        for (int mt = 0; mt < 2; mt++) {
          const int r = wm * 32 + mt * 16 + frow;
          af[kk][mt] = *reinterpret_cast<const f16x8*>(
              As + r * 64 + ((kk * 32 + fq * 8) ^ ((r & 7) << 3)));
        }
#pragma unroll
        for (int nt = 0; nt < 4; nt++) {
          const int c = wn * 64 + nt * 16 + frow;
          bf[kk][nt] = *reinterpret_cast<const f16x8*>(
              Bs + c * 64 + ((kk * 32 + fq * 8) ^ ((c & 7) << 3)));
        }
      }
#pragma unroll
      for (int kk = 0; kk < 2; kk++)
#pragma unroll
        for (int mt = 0; mt < 2; mt++)
#pragma unroll
          for (int nt = 0; nt < 4; nt++)
            acc[mt][nt] = __builtin_amdgcn_mfma_f32_16x16x32_f16(
                af[kk][mt], bf[kk][nt], acc[mt][nt], 0, 0, 0);
    }
#pragma unroll
    for (int mt = 0; mt < 2; mt++)
#pragma unroll
      for (int nt = 0; nt < 4; nt++) {
        const int col = col0 + wn * 64 + nt * 16 + frow;
#pragma unroll
        for (int r = 0; r < 4; r++) {
          const int row = row0 + wm * 32 + mt * 16 + fq * 4 + r;
          kv16[(size_t)row * KVW + col] = (_Float16)acc[mt][nt][r];
        }
      }
  } else if (idx < 320) {
    // ---- qproj: q[r, n0:n0+128] += tn[r, c0:c0+256] @ Wq[c0:c0+256, n] ----
    float* tn_s = (float*)smem;              // 8 rows x 256 c = 8 KB
    const int j = idx - 256;                 // 0..63
    const int b = j >> 5, nt = (j >> 2) & 7, cc = j & 3;
    const int n0 = nt * 128, c0 = cc * 256;
    const int n = tid & 127, cs = tid >> 7;  // 4 c-subchunks of 64
    const int cnt = min(seg[b * 2 + 1], RMAX);
    for (int r0 = 0; r0 < cnt; r0 += 8) {
      const int rows = min(8, cnt - r0);
      for (int i = tid; i < 8 * 256; i += 512) {
        const int r = i >> 8, c = i & 255;
        tn_s[i] = (r < rows) ? tn[(size_t)(b * RMAX + r0 + r) * DIM + c0 + c]
                             : 0.f;
      }
      __syncthreads();
      float acc[8] = {};
      for (int ci = 0; ci < 64; ci++) {
        const int c = cs * 64 + ci;
        const float w = Wq[(size_t)(c0 + c) * DIM + n0 + n];
#pragma unroll
        for (int rr = 0; rr < 8; rr++) acc[rr] += tn_s[rr * 256 + c] * w;
      }
      for (int rr = 0; rr < rows; rr++)
        atomicAdd(&qbuf[(size_t)(b * RMAX + r0 + rr) * DIM + n0 + n], acc[rr]);
      __syncthreads();
    }
  } else {
    // ---- obar: obar[b,e] += vbar[b, c0:c0+128] @ Wo[c0:c0+128, e] ----
    float* vb_s = (float*)smem;              // 128 f32
    const int j = idx - 320;                 // 0..31
    const int b = j >> 4, et = (j >> 3) & 1, cc = j & 7;
    const int e = et * 512 + tid;
    const int c0 = cc * 128;
    if (tid < 128) vb_s[tid] = vbar[b * DIM + c0 + tid];
    __syncthreads();
    float s = 0.f;
    for (int c = 0; c < 128; c++)
      s += vb_s[c] * Wo[(size_t)(c0 + c) * DIM + e];
    atomicAdd(&obar[b * DIM + e], s);
  }
}

// ---------------------------------------------------------------------------
// K4: blocks 0..4095    : fill (zero / obar / fallback)
//     blocks 4096..5119 : attnh (q from qbuf, scores, softmax, PV,
//                         fused per-head oproj -> atomicAdd into out)
// ---------------------------------------------------------------------------
__global__ __launch_bounds__(256) void k4_fill_attn(
    const float* __restrict__ text, const _Float16* __restrict__ kv16,
    const float* __restrict__ Wq, const float* __restrict__ Wo,
    const float* __restrict__ gamma, const float* __restrict__ beta,
    const int* __restrict__ tt, const int* __restrict__ seg,
    const float* __restrict__ obar, const float* __restrict__ qbuf,
    float* __restrict__ out) {
  __shared__ float red[256];
  __shared__ float pbuf[256];
  const int idx = blockIdx.x;
  const int tid = threadIdx.x;
  if (idx < BATCH * NTXT) {
    const int b = idx >> 11;
    const int i = idx & (NTXT - 1);
    const int t = tt[b * NTXT + i];
    float* orow = out + (size_t)(b * NTXT + i) * DIM;
    if (t == 0) {
      for (int c = tid; c < DIM; c += 256) orow[c] = 0.f;
      return;
    }
    if (t > TMED) {
      const float* ob = obar + b * DIM;
      for (int c = tid; c < DIM; c += 256) orow[c] = ob[c];
      return;
    }
    if (i - seg[b * 2] < RMAX) return;
    // ---- slow fallback (unreachable for realistic data) ----
    __shared__ float tns[DIM];
    __shared__ float qrow[DIM];
    __shared__ float oaccs[DIM];
    const float* xrow = text + (size_t)(b * NTXT + i) * DIM;
    float x[4];
    float s = 0.f;
#pragma unroll
    for (int u = 0; u < 4; u++) { x[u] = xrow[tid + 256 * u]; s += x[u]; }
    red[tid] = s; __syncthreads();
    for (int st = 128; st > 0; st >>= 1) {
      if (tid < st) red[tid] += red[tid + st];
      __syncthreads();
    }
    const float mu = red[0] * (1.0f / DIM); __syncthreads();
    float vs = 0.f;
#pragma unroll
    for (int u = 0; u < 4; u++) { float d = x[u] - mu; vs += d * d; }
    red[tid] = vs; __syncthreads();
    for (int st = 128; st > 0; st >>= 1) {
      if (tid < st) red[tid] += red[tid + st];
      __syncthreads();
    }
    const float rstd = rsqrtf(red[0] * (1.0f / DIM) + 1e-5f); __syncthreads();
#pragma unroll
    for (int u = 0; u < 4; u++) {
      const int c = tid + 256 * u;
      tns[c] = (x[u] - mu) * rstd * gamma[c] + beta[c];
    }
    __syncthreads();
    {
      float qa[4] = {0.f, 0.f, 0.f, 0.f};
      for (int c = 0; c < DIM; c++) {
        const float tv = tns[c];
        const float* w = Wq + (size_t)c * DIM + tid;
#pragma unroll
        for (int u = 0; u < 4; u++) qa[u] += tv * w[256 * u];
      }
#pragma unroll
      for (int u = 0; u < 4; u++) qrow[tid + 256 * u] = qa[u];
    }
    __syncthreads();
    const size_t kvrow0 = (size_t)(b * TM + (t - 1) * MMED) * KVW;
    const int d0 = tid & 63, g = tid >> 6;
    for (int h = 0; h < NH; h++) {
      const _Float16* krow = kv16 + kvrow0 + (size_t)tid * KVW + h * DHD;
      float sc = 0.f;
#pragma unroll
      for (int d = 0; d < DHD; d++) sc += qrow[h * DHD + d] * (float)krow[d];
      sc *= 0.125f;
      red[tid] = sc; __syncthreads();
      for (int st = 128; st > 0; st >>= 1) {
        if (tid < st) red[tid] = fmaxf(red[tid], red[tid + st]);
        __syncthreads();
      }
      const float mx = red[0]; __syncthreads();
      const float e = __expf(sc - mx);
      red[tid] = e; __syncthreads();
      for (int st = 128; st > 0; st >>= 1) {
        if (tid < st) red[tid] += red[tid + st];
        __syncthreads();
      }
      const float inv = 1.0f / red[0]; __syncthreads();
      pbuf[tid] = e * inv; __syncthreads();
      const _Float16* vbase = kv16 + kvrow0 + (size_t)(g * 64) * KVW + DIM + h * DHD + d0;
      float a = 0.f;
#pragma unroll 8
      for (int jj = 0; jj < 64; jj++) a += pbuf[g * 64 + jj] * (float)vbase[(size_t)jj * KVW];
      red[tid] = a; __syncthreads();
      if (tid < 64)
        oaccs[h * DHD + tid] = red[tid] + red[64 + tid] + red[128 + tid] + red[192 + tid];
      __syncthreads();
    }
    float oa[4] = {0.f, 0.f, 0.f, 0.f};
    for (int c = 0; c < DIM; c++) {
      const float ov = oaccs[c];
      const float* w = Wo + (size_t)c * DIM + tid;
#pragma unroll
      for (int u = 0; u < 4; u++) oa[u] += ov * w[256 * u];
    }
#pragma unroll
    for (int u = 0; u < 4; u++) orow[tid + 256 * u] = oa[u];
  } else {
    // ---- attnh with fused per-head output projection ----
    __shared__ float qs[DHD];
    __shared__ float osl[DHD];
    const int j = idx - BATCH * NTXT;       // 0..1023
    const int h = j & 15, rt = (j >> 4) & 31, b = j >> 9;
    const int i0 = seg[b * 2];
    const int cnt = min(seg[b * 2 + 1], RMAX);
    const int d0 = tid & 63, g = tid >> 6;
    for (int r = rt; r < cnt; r += RT) {
      const int i = i0 + r;
      const int t = tt[b * NTXT + i];       // in [1, TMED]
      if (tid < 64) qs[tid] = qbuf[(size_t)(b * RMAX + r) * DIM + h * DHD + tid];
      __syncthreads();
      const size_t kvrow0 = (size_t)(b * TM + (t - 1) * MMED) * KVW;
      const _Float16* krow = kv16 + kvrow0 + (size_t)tid * KVW + h * DHD;
      float sc = 0.f;
#pragma unroll
      for (int d = 0; d < DHD; d += 8) {
        const f16x8 kk = *reinterpret_cast<const f16x8*>(krow + d);
#pragma unroll
        for (int u = 0; u < 8; u++) sc += qs[d + u] * (float)kk[u];
      }
      sc *= 0.125f;
      red[tid] = sc; __syncthreads();
      for (int st = 128; st > 0; st >>= 1) {
        if (tid < st) red[tid] = fmaxf(red[tid], red[tid + st]);
        __syncthreads();
      }
      const float mx = red[0]; __syncthreads();
      const float e = __expf(sc - mx);
      red[tid] = e; __syncthreads();
      for (int st = 128; st > 0; st >>= 1) {
        if (tid < st) red[tid] += red[tid + st];
        __syncthreads();
      }
      const float inv = 1.0f / red[0]; __syncthreads();
      pbuf[tid] = e * inv; __syncthreads();
      const _Float16* vbase = kv16 + kvrow0 + (size_t)(g * 64) * KVW + DIM + h * DHD + d0;
      float a = 0.f;
#pragma unroll 8
      for (int jj = 0; jj < 64; jj++) a += pbuf[g * 64 + jj] * (float)vbase[(size_t)jj * KVW];
      red[tid] = a; __syncthreads();
      if (tid < 64)
        osl[tid] = red[tid] + red[64 + tid] + red[128 + tid] + red[192 + tid];
      __syncthreads();
      // fused partial oproj: out[i,:] += osl @ Wo[h*64 : h*64+64, :]
      float* orow = out + (size_t)(b * NTXT + i) * DIM;
#pragma unroll
      for (int u = 0; u < 4; u++) {
        const int c = tid + 256 * u;
        const float* w = Wo + (size_t)(h * DHD) * DIM + c;
        float s2 = 0.f;
#pragma unroll 8
        for (int d = 0; d < DHD; d++) s2 += osl[d] * w[(size_t)d * DIM];
        atomicAdd(&orow[c], s2);
      }
      __syncthreads();
    }
  }
}

// ---------------------------------------------------------------------------
extern "C" void kernel_launch(void* const* d_in, const int* in_sizes, int n_in,
                              void* d_out, int out_size, void* d_ws, size_t ws_size,
                              hipStream_t stream) {
  const float* text  = (const float*)d_in[0];
  const float* image = (const float*)d_in[1];
  const int*   loc   = (const int*)d_in[2];
  const float* Wq    = (const float*)d_in[3];
  const float* Wkv   = (const float*)d_in[4];
  const float* Wo    = (const float*)d_in[5];
  const float* gamma = (const float*)d_in[6];
  const float* beta  = (const float*)d_in[7];
  float* out = (float*)d_out;

  // ws layout: kv16 8MB | WkvT 4MB | img16 4MB | tn 2MB |
  //            [k1-zeroed: qbuf 2MB | vbar | obar] | tt | seg | ipart 1MB
  _Float16* kv16  = (_Float16*)d_ws;
  _Float16* WkvT  = kv16 + (size_t)BATCH * TM * KVW;
  _Float16* img16 = WkvT + (size_t)KVW * DIM;
  float*    tn    = (float*)(img16 + (size_t)BATCH * TM * DIM);
  float*    qbuf  = tn + (size_t)BATCH * RMAX * DIM;
  float*    vbar  = qbuf + (size_t)BATCH * RMAX * DIM;
  float*    obar  = vbar + BATCH * DIM;
  int*      tt    = (int*)(obar + BATCH * DIM);
  int*      seg   = tt + BATCH * NTXT;
  float*    ipart = (float*)(seg + 8);                 // 256*1024 f32 = 1MB

  k1_scan_cvt_tr<<<BATCH + 256 + 512 + 16, 1024, 0, stream>>>(
      loc, image, Wkv, tt, seg, ipart, img16, WkvT, qbuf);
  k2_prep<<<130, 256, 0, stream>>>(Wkv, text, gamma, beta, seg, ipart,
                                   tn, vbar, out);
  k3_gemm_qproj_obar<<<352, 512, 0, stream>>>(img16, WkvT, Wq, Wo, tn, vbar,
                                              seg, kv16, qbuf, obar);
  k4_fill_attn<<<BATCH * NTXT + NH * RT * BATCH, 256, 0, stream>>>(
      text, kv16, Wq, Wo, gamma, beta, tt, seg, obar, qbuf, out);
}